// Round 13
// baseline (256.231 us; speedup 1.0000x reference)
//
#include <hip/hip_runtime.h>
#include <cstdint>
#include <cstddef>

// Problem constants (fixed by reference shapes)
#define T_    4
#define B_    2
#define NW_   64
#define WS_   128
#define C_    256
#define NC3   768
#define H_    8
#define HD_   32
#define TOPK_ 4
#define RCAP  131072
#define BAND  0.008f
#define RBCAP 512          // per-block LDS rescue staging capacity

// Workspace layout (bytes, all 16B aligned).
// A2/Bq/Bp are stored FRAGMENT-MAJOR: the exact 16x16x32-bf16 MFMA operand
// register layout (lane = (m|n)&15 | octet<<4, 8 contiguous shorts per lane).
// qkv GEMM is 2-TERM bf16x2 (A_hi*W_hi + A_lo*W_hi); band 0.008 = 7.1 sigma;
// borderline outputs go to the lane-parallel serial-fp32 rescue.
// R2: same-address device atomics serialize; rescue is LDS-staged.
// R4: in-block p-loop => acc spill to scratch.
// R5: attn_proj qr-fold regressed; stays at 2048-block version.
// R6: occupancy 21->31% moved qkv only 102->95us -> not TLP-bound.
// R7: LDS-staged qkv (global_load_lds, m97 pattern) 95->82us. qkv FROZEN.
// R8: scattered 16B stores => 2.6x write amplification (168MB).
// R9: k_split store mapping validated (wave stores = contiguous 1KB row);
//     but separate kernel's 2nd x read cost more than it saved.
// R10: merged prep kernels; kcs folded into attn_proj. 230us.
// R11: per-lane sparsity skip NULL on wave64 (wave executes every body).
// R12: attn reduce moved to MFMA (exact integer arithmetic) -> 217us.
// R13: k_prep split path uses R9's coalesced mapping FUSED (one x read,
// LDS psum reduce for part); region+scores folded into rescue launch
// (2 extra blocks). 8 -> 6 launches.
#define OFF_A2     0ull            // [mb][gi 0..7][ktA 0..15][lane][8] = 64 MB
#define OFF_BQ     67108864ull     // [gj 0..47][ktB 0..7][lane][8] = 393,216 (hi only)
#define OFF_BP     67502080ull     // [gj 0..15][ktB 0..23][lane][8] = 393,216 (3-term)
#define OFF_QM     67895296ull     // qmask u32 [g][s][h] = 2,097,152
#define OFF_KB     69992448ull     // 2,097,152
#define OFF_VB     72089600ull     // 2,097,152
#define OFF_KV     74186752ull     // kvf bf16 2-term B-frags = 16,777,216
#define OFF_PART   91488256ull     // 524,288
#define OFF_IDX    92143616ull     // 2,048
#define OFF_RL     92145664ull     // 524,288 (131072 entries)
#define OFF_RC     92669952ull     // 16

typedef short short8 __attribute__((ext_vector_type(8)));
typedef float floatx4 __attribute__((ext_vector_type(4)));

__device__ __forceinline__ short f2bf(float f) {
    unsigned u = __float_as_uint(f);
    unsigned r = (u + 0x7fffu + ((u >> 16) & 1u)) >> 16;
    return (short)r;
}
__device__ __forceinline__ float bf2f(short h) {
    return __uint_as_float(((unsigned)(unsigned short)h) << 16);
}

__device__ __forceinline__ void gload_lds16(const void* g, void* l) {
    __builtin_amdgcn_global_load_lds(
        (const __attribute__((address_space(1))) unsigned*)g,
        (__attribute__((address_space(3))) unsigned*)l,
        16, 0, 0);
}

// g = (t*B_+b)*NW_ + n, s in [0,128): float index of x[t,b,lt,lh,lw,0]
__device__ __forceinline__ int xoff_row(int g, int s) {
    int tb = g >> 6;
    int n  = g & 63;
    int iwt = n >> 4, iwh = (n >> 2) & 3, iww = n & 3;
    int ipt = s >> 6, iph = (s >> 3) & 7, ipw = s & 7;
    int lt = iwt * 2 + ipt, lh = iwh * 8 + iph, lw = iww * 8 + ipw;
    return (((tb * 8 + lt) * 32 + lh) * 32 + lw) * 256;
}

// ---- PREP: one launch, three independent jobs branched on blockIdx.
// blocks 0..511: A2 split via R9's PERFECTLY-COALESCED mapping (lane L
// handles s = sblk*16+(L&15), c = kt*32+(L>>4)*8+j; slot==L, wave stores =
// one contiguous 1KB row/instr) FUSED with partial sums via LDS psum.
__global__ __launch_bounds__(256) void k_prep(const float* __restrict__ x,
        const float* __restrict__ Wqkv, const float* __restrict__ Wp,
        float* __restrict__ part, short* __restrict__ A2,
        short* __restrict__ Bq, short* __restrict__ Bp) {
    __shared__ float psum[256][64];
    const int bid = blockIdx.x;
    const int tid = threadIdx.x;
    if (bid < 512) {
        int g = bid;
        int w = tid >> 6, L = tid & 63;
        int l15 = L & 15, oq = L >> 4;
        float acc[64];
#pragma unroll
        for (int q = 0; q < 64; ++q) acc[q] = 0.f;
        for (int sb2 = 0; sb2 < 2; ++sb2) {
            int sblk = w * 2 + sb2;
            int s = sblk * 16 + l15;
            const float* xr = x + xoff_row(g, s);
            size_t rowb = ((size_t)(g * 8 + sblk)) * 16;
#pragma unroll
            for (int kt = 0; kt < 8; ++kt) {
                int c0 = kt * 32 + oq * 8;
                float4 v0 = *(const float4*)(xr + c0);
                float4 v1 = *(const float4*)(xr + c0 + 4);
                float vv[8] = {v0.x, v0.y, v0.z, v0.w, v1.x, v1.y, v1.z, v1.w};
                short8 hi, lo;
#pragma unroll
                for (int j = 0; j < 8; ++j) {
                    acc[kt * 8 + j] += vv[j];
                    short h = f2bf(vv[j]);
                    hi[j] = h;
                    lo[j] = f2bf(vv[j] - bf2f(h));
                }
                *(short8*)&A2[(rowb + kt) * 512 + (size_t)L * 8] = hi;
                *(short8*)&A2[(rowb + 8 + kt) * 512 + (size_t)L * 8] = lo;
            }
        }
#pragma unroll
        for (int q = 0; q < 64; ++q) psum[tid][q] = acc[q];
        __syncthreads();
        // part[c] = sum over the 64 contributing threads (4 w x 16 l15)
        int c = tid;
        int ktc = c >> 5, oqc = (c >> 3) & 3, jc = c & 7;
        float tot = 0.f;
        for (int ww = 0; ww < 4; ++ww)
#pragma unroll
            for (int l = 0; l < 16; ++l)
                tot += psum[ww * 64 + oqc * 16 + l][ktc * 8 + jc];
        part[g * C_ + c] = tot;
    } else if (bid < 1280) {
        // b_build_qkv: u = ke + 256*ny
        int u = bid - 512;
        int ke = u & 255;
        int n = (u >> 8) * 256 + tid;
        float wv = Wqkv[(size_t)ke * NC3 + n];
        short o = f2bf(wv);
        int gj = n >> 4, lmn = n & 15, ktB = ke >> 5, oct = (ke >> 3) & 3, sub = ke & 7;
        Bq[(size_t)((gj * 8 + ktB) * 64 + (lmn | (oct << 4))) * 8 + sub] = o;
    } else {
        // b_build_proj
        int ke = bid - 1280;               // 0..767
        int n = tid;
        float wv = Wp[(size_t)(ke & 255) * 256 + n];
        short hi = f2bf(wv);
        short o = (ke < 512) ? hi : f2bf(wv - bf2f(hi));
        int gj = n >> 4, lmn = n & 15, ktB = ke >> 5, oct = (ke >> 3) & 3, sub = ke & 7;
        Bp[(size_t)((gj * 24 + ktB) * 64 + (lmn | (oct << 4))) * 8 + sub] = o;
    }
}

__device__ __forceinline__ unsigned p4(unsigned xv) {
    return (xv & 1u) | ((xv >> 7) & 2u) | ((xv >> 14) & 4u) | ((xv >> 21) & 8u);
}

// ---- K3: qkv GEMM, LDS-staged (m97 pattern). FROZEN (R7, 82 us).
__global__ __launch_bounds__(256, 2) void qkv_mfma(const short* __restrict__ A2,
        const short* __restrict__ Bq, const float* __restrict__ bias,
        unsigned* __restrict__ qm, unsigned* __restrict__ kb,
        unsigned* __restrict__ vb, unsigned* __restrict__ rl,
        unsigned* __restrict__ rcnt) {
    __shared__ __align__(16) char stg[2][32768];   // staging; [0] reused as sp
    __shared__ unsigned rbuf[RBCAP];
    __shared__ unsigned lcnt, sbase;
    const int bid = blockIdx.x;            // 0..1535
    const int x8 = bid & 7;
    const int y = bid >> 3;                // 0..191
    const int p = y % 3;
    const int mb = x8 + ((y / 3) << 3);    // bijective: all (mb,p) covered
    const int tid = threadIdx.x;
    const int wv = tid >> 6, lane = tid & 63;
    const int wm = wv >> 1, wn = wv & 1;
    const int lm = lane & 15, lq = lane >> 4;

    if (tid == 0) lcnt = 0;

    const char* Ag = (const char*)(A2 + (size_t)mb * 65536);   // 128 KB slice
    const char* Bg = (const char*)(Bq + (size_t)p * 65536);    // 128 KB slice
    const int laneoff = lane * 16;

#define STAGE_CHUNK(buf, ktB_)                                                 \
    {                                                                          \
        _Pragma("unroll")                                                      \
        for (int k = 0; k < 4; ++k) {                                          \
            int slot = k * 4 + wv;                                             \
            int gi = slot >> 1, hl = slot & 1;                                 \
            const char* src = Ag + (((gi * 16) + (ktB_) + hl * 8) << 10) + laneoff; \
            gload_lds16(src, &stg[buf][k * 4096 + wv * 1024 + laneoff]);       \
        }                                                                      \
        _Pragma("unroll")                                                      \
        for (int k = 0; k < 4; ++k) {                                          \
            int slot = k * 4 + wv;                                             \
            const char* src = Bg + ((slot * 8 + (ktB_)) << 10) + laneoff;      \
            gload_lds16(src, &stg[buf][16384 + k * 4096 + wv * 1024 + laneoff]); \
        }                                                                      \
    }

    floatx4 acc[4][8];
#pragma unroll
    for (int i = 0; i < 4; ++i)
#pragma unroll
        for (int j = 0; j < 8; ++j) acc[i][j] = (floatx4)0.f;

    STAGE_CHUNK(0, 0);
    __syncthreads();                       // drains stage 0 (vmcnt(0))

    for (int ktB = 0; ktB < 8; ++ktB) {
        int cur = ktB & 1;
        if (ktB < 7) STAGE_CHUNK(cur ^ 1, ktB + 1);
        const char* sb = &stg[cur][0];
        short8 ah[4], al[4], bf[8];
#pragma unroll
        for (int j = 0; j < 8; ++j)
            bf[j] = *(const short8*)(sb + 16384 + ((wn * 8 + j) << 10) + laneoff);
#pragma unroll
        for (int i = 0; i < 4; ++i) {
            ah[i] = *(const short8*)(sb + (((wm * 4 + i) * 2 + 0) << 10) + laneoff);
            al[i] = *(const short8*)(sb + (((wm * 4 + i) * 2 + 1) << 10) + laneoff);
        }
#pragma unroll
        for (int i = 0; i < 4; ++i)
#pragma unroll
            for (int j = 0; j < 8; ++j)
                acc[i][j] = __builtin_amdgcn_mfma_f32_16x16x32_bf16(
                    ah[i], bf[j], acc[i][j], 0, 0, 0);
#pragma unroll
        for (int i = 0; i < 4; ++i)
#pragma unroll
            for (int j = 0; j < 8; ++j)
                acc[i][j] = __builtin_amdgcn_mfma_f32_16x16x32_bf16(
                    al[i], bf[j], acc[i][j], 0, 0, 0);
        __syncthreads();   // all waves done reading cur; next stage drained
    }

    // epilogue: spikes into LDS (sp aliases stg); borderline -> rescue staging
    unsigned char* sp = (unsigned char*)&stg[0][0];   // 128*264 = 33792 <= 65536
#pragma unroll
    for (int i = 0; i < 4; ++i) {
#pragma unroll
        for (int j = 0; j < 8; ++j) {
            int cb = wn * 128 + j * 16 + lm;
            int cg = p * 256 + cb;
            float bj = bias[cg];
#pragma unroll
            for (int r = 0; r < 4; ++r) {
                int s = wm * 64 + i * 16 + lq * 4 + r;
                float v = acc[i][j][r] + bj;
                if (fabsf(v - 2.0f) < BAND) {
                    unsigned ent = ((unsigned)mb << 17) | ((unsigned)s << 10) | (unsigned)cg;
                    unsigned slot = atomicAdd(&lcnt, 1u);
                    if (slot < RBCAP) {
                        rbuf[slot] = ent;
                    } else {                       // overflow fallback (cold)
                        unsigned gs = atomicAdd(rcnt, 1u);
                        if (gs < RCAP) rl[gs] = ent;
                    }
                }
                sp[s * 264 + cb] = (v >= 2.0f) ? 1 : 0;
            }
        }
    }
    __syncthreads();

    // bulk-reserve rescue slots: ONE global atomic per block
    unsigned cnt = lcnt;
    if (cnt > RBCAP) cnt = RBCAP;
    if (tid == 0) sbase = atomicAdd(rcnt, cnt);
    __syncthreads();
    for (unsigned e = tid; e < cnt; e += 256) {
        unsigned slot = sbase + e;
        if (slot < RCAP) rl[slot] = rbuf[e];
    }

    if (p == 0) {
        // pack q bitmasks over channel-within-head: qm[g][s][h]
        const unsigned* spw = (const unsigned*)sp;   // pitch 66 words
#pragma unroll
        for (int t = 0; t < 4; ++t) {
            int w = t * 256 + tid;
            int s = w >> 3, h = w & 7;
            unsigned m = 0;
#pragma unroll
            for (int q = 0; q < 8; ++q)
                m |= p4(spw[s * 66 + h * 8 + q]) << (q * 4);
            qm[(size_t)mb * 1024 + w] = m;
        }
    } else {
        // pack k/v bitmasks along s: (kb|vb)[(mb*256+c)*4 + w2]
        unsigned wrd[4];
#pragma unroll
        for (int w2 = 0; w2 < 4; ++w2) {
            unsigned m = 0;
#pragma unroll
            for (int ii = 0; ii < 32; ++ii)
                m |= (unsigned)(sp[(w2 * 32 + ii) * 264 + tid] & 1) << ii;
            wrd[w2] = m;
        }
        uint4 o; o.x = wrd[0]; o.y = wrd[1]; o.z = wrd[2]; o.w = wrd[3];
        *(uint4*)(((p == 1) ? kb : vb) + ((size_t)mb * 256 + tid) * 4) = o;
    }
}

// ---- rescue (blocks 0..255) + region/scores (blocks 256..257).
// rescue: lane-parallel serial ascending-k fp32 FMA per entry (validated).
// region/scores: one block per batch b; region in LDS, same dot order
// (ascending c) and same strict-> ascending-j top-4 tie-break as before.
__global__ __launch_bounds__(256) void rescue_rs(const float* __restrict__ x,
        const float* __restrict__ W, const float* __restrict__ bias,
        const unsigned* __restrict__ rl, const unsigned* __restrict__ rcnt,
        unsigned* __restrict__ qm, unsigned* __restrict__ kb,
        unsigned* __restrict__ vb, const float* __restrict__ part,
        int* __restrict__ idx) {
    __shared__ float reg[64][256];     // 64 KB (region/scores path only)
    __shared__ float sc2[64][64];      // 16 KB
    const int bid = blockIdx.x;
    const int tid = threadIdx.x;
    if (bid >= 256) {
        int b = bid - 256;             // 0..1
        for (int n = 0; n < 64; ++n) {
            float a = 0.f;
#pragma unroll
            for (int t = 0; t < 4; ++t)
                a += part[((t * 2 + b) * 64 + n) * C_ + tid];
            reg[n][tid] = a * (1.0f / 128.0f);
        }
        __syncthreads();
        for (int k = 0; k < 16; ++k) {
            int id = tid * 16 + k;
            int i = id >> 6, j = id & 63;
            float dot = 0.f;
            for (int c = 0; c < C_; ++c) dot += reg[i][c] * reg[j][c];
            sc2[i][j] = dot * 0.17677669529663687f;
        }
        __syncthreads();
        if (tid < 64) {
            for (int kk = 0; kk < TOPK_; ++kk) {
                float best = -INFINITY; int bj = 0;
                for (int j = 0; j < 64; ++j)
                    if (sc2[tid][j] > best) { best = sc2[tid][j]; bj = j; }
                idx[(b * 64 + tid) * TOPK_ + kk] = bj;
                sc2[tid][bj] = -INFINITY;
            }
        }
        return;
    }
    unsigned n = *rcnt; if (n > RCAP) n = RCAP;
    unsigned gid = bid * 256 + tid;
    for (unsigned e = gid; e < n; e += 65536u) {
        unsigned ent = rl[e];
        int mb = ent >> 17, s = (ent >> 10) & 127, cg = ent & 1023;
        const float* ar = x + xoff_row(mb, s);
        const float* wc = W + cg;
        float da = 0.f;
#pragma unroll 4
        for (int k4 = 0; k4 < 64; ++k4) {
            float4 a4 = *(const float4*)(ar + k4 * 4);
            da = fmaf(a4.x, wc[(size_t)(k4 * 4 + 0) * NC3], da);
            da = fmaf(a4.y, wc[(size_t)(k4 * 4 + 1) * NC3], da);
            da = fmaf(a4.z, wc[(size_t)(k4 * 4 + 2) * NC3], da);
            da = fmaf(a4.w, wc[(size_t)(k4 * 4 + 3) * NC3], da);
        }
        da += bias[cg];
        int spk = (da >= 2.0f) ? 1 : 0;
        if (cg < 256) {
            int h = cg >> 5, d = cg & 31;
            unsigned* wp = qm + (size_t)mb * 1024 + s * 8 + h;
            unsigned bit = 1u << d;
            int have = (*wp & bit) ? 1 : 0;
            if (have != spk) atomicXor(wp, bit);
        } else {
            unsigned* tgt = (cg < 512) ? kb : vb;
            int c = cg & 255;
            unsigned* wp = tgt + ((size_t)mb * 256 + c) * 4 + (s >> 5);
            unsigned bit = 1u << (s & 31);
            int have = (*wp & bit) ? 1 : 0;
            if (have != spk) atomicXor(wp, bit);
        }
    }
}

// ---- K4: kv = popcount over gathered s-bitmasks (exact int <= 512),
// written PRE-PACKED as bf16 2-term B-fragments for the attn MFMA.
__global__ __launch_bounds__(256) void kv_bits(const unsigned* __restrict__ kb,
        const unsigned* __restrict__ vb, const int* __restrict__ idx,
        short* __restrict__ kvf) {
    int g = blockIdx.x;            // 512
    int tb = g >> 6, n = g & 63, b = tb & 1;
    int tid = threadIdx.x;
    __shared__ uint4 kbl[1024];
    __shared__ uint4 vbl[1024];
    __shared__ int widx[TOPK_];
    if (tid < TOPK_) widx[tid] = idx[(b * 64 + n) * TOPK_ + tid];
    __syncthreads();
#pragma unroll
    for (int kk = 0; kk < TOPK_; ++kk) {
        int g2 = tb * 64 + widx[kk];
        kbl[kk * 256 + tid] = *(const uint4*)&kb[((size_t)g2 * 256 + tid) * 4];
        vbl[kk * 256 + tid] = *(const uint4*)&vb[((size_t)g2 * 256 + tid) * 4];
    }
    __syncthreads();
    int h = tid >> 5, e = tid & 31;
    int ei = e >> 4;
    uint4 vw0 = vbl[0 * 256 + h * 32 + e];
    uint4 vw1 = vbl[1 * 256 + h * 32 + e];
    uint4 vw2 = vbl[2 * 256 + h * 32 + e];
    uint4 vw3 = vbl[3 * 256 + h * 32 + e];
#pragma unroll
    for (int oct = 0; oct < 4; ++oct) {
        short8 hi8, lo8;
#pragma unroll
        for (int dd = 0; dd < 8; ++dd) {
            int d = oct * 8 + dd;
            uint4 k0 = kbl[0 * 256 + h * 32 + d];
            uint4 k1 = kbl[1 * 256 + h * 32 + d];
            uint4 k2 = kbl[2 * 256 + h * 32 + d];
            uint4 k3 = kbl[3 * 256 + h * 32 + d];
            int acc = __popc(k0.x & vw0.x) + __popc(k0.y & vw0.y)
                    + __popc(k0.z & vw0.z) + __popc(k0.w & vw0.w)
                    + __popc(k1.x & vw1.x) + __popc(k1.y & vw1.y)
                    + __popc(k1.z & vw1.z) + __popc(k1.w & vw1.w)
                    + __popc(k2.x & vw2.x) + __popc(k2.y & vw2.y)
                    + __popc(k2.z & vw2.z) + __popc(k2.w & vw2.w)
                    + __popc(k3.x & vw3.x) + __popc(k3.y & vw3.y)
                    + __popc(k3.z & vw3.z) + __popc(k3.w & vw3.w);
            float v = (float)acc;
            short hv = f2bf(v);            // exact split: lo in {-1,0,1}
            hi8[dd] = hv;
            lo8[dd] = f2bf(v - bf2f(hv));
        }
        int ln = (e & 15) | (oct << 4);
        *(short8*)&kvf[((((size_t)g * 8 + h) * 2 + 0) * 2 + ei) * 512 + ln * 8] = hi8;
        *(short8*)&kvf[((((size_t)g * 8 + h) * 2 + 1) * 2 + ei) * 512 + ln * 8] = lo8;
    }
}

// ---- K5: FUSED attn + proj. One block = 32 rows of one window g. ----
// R12: attn phase on MFMA. num = Q x (KVhi + KVlo), den via 32 cndmask-adds.
// Exact integer arithmetic -> bit-identical r.
__global__ __launch_bounds__(256) void attn_proj(const unsigned* __restrict__ qm,
        const short* __restrict__ kvf, const unsigned* __restrict__ kb,
        const int* __restrict__ idx, const short* __restrict__ Bp,
        const float* __restrict__ bias, float* __restrict__ out) {
    __shared__ __align__(16) short aw[16384];   // 32 KB frags; reused as float ow[32][256]
    __shared__ unsigned qb[256];
    __shared__ float ksl[256];
    __shared__ float denl[256];
    __shared__ int widx[TOPK_];
    const int bid = blockIdx.x;        // 2048
    const int g = bid >> 2, qr = bid & 3;
    const int tb = g >> 6, n = g & 63, b = tb & 1;
    const int tid = threadIdx.x;
    if (tid < TOPK_) widx[tid] = idx[(b * 64 + n) * TOPK_ + tid];
    __syncthreads();
    float ks = 0.f;
#pragma unroll
    for (int kk = 0; kk < TOPK_; ++kk) {
        uint4 kw = *(const uint4*)&kb[((size_t)(tb * 64 + widx[kk]) * 256 + tid) * 4];
        ks += (float)(__popc(kw.x) + __popc(kw.y) + __popc(kw.z) + __popc(kw.w));
    }
    ksl[tid] = ks;
    qb[tid] = qm[(size_t)g * 1024 + qr * 256 + tid];
    __syncthreads();

    // den[h][sl]: one thread per (h, sl); ascending-d adds of exact integers
    {
        int h = tid >> 5, sl = tid & 31;
        unsigned qw = qb[sl * 8 + h];
        float den = 0.f;
#pragma unroll
        for (int d = 0; d < 32; ++d)
            den += ((qw >> d) & 1u) ? ksl[h * 32 + d] : 0.f;
        denl[tid] = den;
    }
    __syncthreads();

    const int wvw = tid >> 6, lane = tid & 63;
    const int oct = lane >> 4, l15 = lane & 15;

    // attn MFMA: wave owns heads {2*wvw, 2*wvw+1}
    floatx4 nacc[2][2][2];   // [h2][mi][ei]
#pragma unroll
    for (int h2 = 0; h2 < 2; ++h2)
#pragma unroll
        for (int mi = 0; mi < 2; ++mi)
#pragma unroll
            for (int ei = 0; ei < 2; ++ei) nacc[h2][mi][ei] = (floatx4)0.f;

#pragma unroll
    for (int h2 = 0; h2 < 2; ++h2) {
        int h = wvw * 2 + h2;
        // A-frags: Q bits -> bf16 {0, 1.0}; lane holds k = oct*8 + j
        short8 a0, a1;
        {
            unsigned byt = (qb[(l15)*8 + h] >> (oct * 8)) & 0xffu;
#pragma unroll
            for (int j = 0; j < 8; ++j)
                a0[j] = ((byt >> j) & 1u) ? (short)0x3F80 : (short)0;
        }
        {
            unsigned byt = (qb[(16 + l15)*8 + h] >> (oct * 8)) & 0xffu;
#pragma unroll
            for (int j = 0; j < 8; ++j)
                a1[j] = ((byt >> j) & 1u) ? (short)0x3F80 : (short)0;
        }
#pragma unroll
        for (int ei = 0; ei < 2; ++ei) {
            short8 bh = *(const short8*)&kvf[((((size_t)g * 8 + h) * 2 + 0) * 2 + ei) * 512 + lane * 8];
            short8 bl = *(const short8*)&kvf[((((size_t)g * 8 + h) * 2 + 1) * 2 + ei) * 512 + lane * 8];
            nacc[h2][0][ei] = __builtin_amdgcn_mfma_f32_16x16x32_bf16(a0, bh, nacc[h2][0][ei], 0, 0, 0);
            nacc[h2][0][ei] = __builtin_amdgcn_mfma_f32_16x16x32_bf16(a0, bl, nacc[h2][0][ei], 0, 0, 0);
            nacc[h2][1][ei] = __builtin_amdgcn_mfma_f32_16x16x32_bf16(a1, bh, nacc[h2][1][ei], 0, 0, 0);
            nacc[h2][1][ei] = __builtin_amdgcn_mfma_f32_16x16x32_bf16(a1, bl, nacc[h2][1][ei], 0, 0, 0);
        }
    }

    // epilogue: divide by den, split hi/lo, write aw A-frags (same layout as old)
#pragma unroll
    for (int h2 = 0; h2 < 2; ++h2) {
        int h = wvw * 2 + h2;
#pragma unroll
        for (int mi = 0; mi < 2; ++mi) {
#pragma unroll
            for (int ei = 0; ei < 2; ++ei) {
                int e = ei * 16 + l15;
                int lane2base = (((e >> 3) & 3) << 4);
                int sub = e & 7;
#pragma unroll
                for (int r = 0; r < 4; ++r) {
                    int sl = mi * 16 + oct * 4 + r;
                    float rv = nacc[h2][mi][ei][r] / (denl[h * 32 + sl] + 1e-6f);
                    short hi = f2bf(rv), lo = f2bf(rv - bf2f(hi));
                    int lane2 = (sl & 15) | lane2base;
                    aw[((mi * 16 + h) * 64 + lane2) * 8 + sub] = hi;
                    aw[((mi * 16 + 8 + h) * 64 + lane2) * 8 + sub] = lo;
                }
            }
        }
    }
    __syncthreads();

    // proj: M=32, N=256; 4 waves each N=64
    const int lm = lane & 15, lq = lane >> 4;
    floatx4 pacc[2][4];
#pragma unroll
    for (int i = 0; i < 2; ++i)
#pragma unroll
        for (int j = 0; j < 4; ++j) pacc[i][j] = (floatx4)0.f;
    const short* Bb = Bp + ((size_t)(wvw * 4) * 24) * 512 + lane * 8;
#pragma unroll 2
    for (int kt = 0; kt < 24; ++kt) {
        int ktA = (kt < 16) ? kt : kt - 16;
        short8 af[2], bf[4];
#pragma unroll
        for (int i = 0; i < 2; ++i)
            af[i] = *(const short8*)&aw[((i * 16 + ktA) * 64 + lane) * 8];
#pragma unroll
        for (int j = 0; j < 4; ++j)
            bf[j] = *(const short8*)(Bb + (size_t)(j * 24 + kt) * 512);
#pragma unroll
        for (int i = 0; i < 2; ++i)
#pragma unroll
            for (int j = 0; j < 4; ++j)
                pacc[i][j] = __builtin_amdgcn_mfma_f32_16x16x32_bf16(
                    af[i], bf[j], pacc[i][j], 0, 0, 0);
    }
    __syncthreads();

    float* ow = (float*)aw;            // 32 x 256 fp32 rows
#pragma unroll
    for (int i = 0; i < 2; ++i) {
#pragma unroll
        for (int j = 0; j < 4; ++j) {
            int c = wvw * 64 + j * 16 + lm;
            float bj = bias[c];
#pragma unroll
            for (int r = 0; r < 4; ++r)
                ow[(i * 16 + lq * 4 + r) * 256 + c] = pacc[i][j][r] + bj;
        }
    }
    __syncthreads();

    // coalesced un-windowize store: rows are contiguous 1 KB in out
    int sl2 = tid >> 3, pc = (tid & 7) * 32;
    int off = xoff_row(g, qr * 32 + sl2) + pc;
#pragma unroll
    for (int q = 0; q < 8; ++q)
        *(float4*)(out + off + q * 4) = *(const float4*)&ow[sl2 * 256 + pc + q * 4];
}

extern "C" void kernel_launch(void* const* d_in, const int* in_sizes, int n_in,
                              void* d_out, int out_size, void* d_ws, size_t ws_size,
                              hipStream_t stream) {
    (void)in_sizes; (void)n_in; (void)out_size; (void)ws_size;
    const float* x    = (const float*)d_in[0];
    const float* Wqkv = (const float*)d_in[1];
    const float* bqkv = (const float*)d_in[2];
    const float* Wp   = (const float*)d_in[3];
    const float* bp   = (const float*)d_in[4];
    char* ws = (char*)d_ws;
    short*    A2    = (short*)   (ws + OFF_A2);
    short*    Bq    = (short*)   (ws + OFF_BQ);
    short*    Bpj   = (short*)   (ws + OFF_BP);
    unsigned* qmv   = (unsigned*)(ws + OFF_QM);
    unsigned* kb    = (unsigned*)(ws + OFF_KB);
    unsigned* vb    = (unsigned*)(ws + OFF_VB);
    short*    kvf   = (short*)   (ws + OFF_KV);
    float*    part  = (float*)   (ws + OFF_PART);
    int*      idxb  = (int*)     (ws + OFF_IDX);
    unsigned* rl    = (unsigned*)(ws + OFF_RL);
    unsigned* rcnt  = (unsigned*)(ws + OFF_RC);
    float*    out   = (float*)d_out;

    hipMemsetAsync(rcnt, 0, 4, stream);
    k_prep     <<<2048, 256, 0, stream>>>(x, Wqkv, Wp, part, A2, Bq, Bpj);
    qkv_mfma   <<<1536, 256, 0, stream>>>(A2, Bq, bqkv, qmv, kb, vb, rl, rcnt);
    rescue_rs  <<<258, 256, 0, stream>>>(x, Wqkv, bqkv, rl, rcnt, qmv, kb, vb, part, idxb);
    kv_bits    <<<512, 256, 0, stream>>>(kb, vb, idxb, kvf);
    attn_proj  <<<2048, 256, 0, stream>>>(qmv, kvf, kb, idxb, Bpj, bp, out);
}

// Round 14
// 216.807 us; speedup vs baseline: 1.1818x; 1.1818x over previous
//
#include <hip/hip_runtime.h>
#include <cstdint>
#include <cstddef>

// Problem constants (fixed by reference shapes)
#define T_    4
#define B_    2
#define NW_   64
#define WS_   128
#define C_    256
#define NC3   768
#define H_    8
#define HD_   32
#define TOPK_ 4
#define RCAP  131072
#define BAND  0.008f
#define RBCAP 512          // per-block LDS rescue staging capacity

// Workspace layout (bytes, all 16B aligned).
// A2/Bq/Bp are stored FRAGMENT-MAJOR: the exact 16x16x32-bf16 MFMA operand
// register layout (lane = (m|n)&15 | octet<<4, 8 contiguous shorts per lane).
// qkv GEMM is 2-TERM bf16x2 (A_hi*W_hi + A_lo*W_hi); band 0.008 = 7.1 sigma;
// borderline outputs go to the lane-parallel serial-fp32 rescue.
// R2: same-address device atomics serialize; rescue is LDS-staged.
// R4: in-block p-loop => acc spill to scratch.
// R5: attn_proj qr-fold regressed; stays at 2048-block version.
// R6: occupancy 21->31% moved qkv only 102->95us -> not TLP-bound.
// R7: LDS-staged qkv (global_load_lds, m97 pattern) 95->82us. qkv FROZEN.
// R8: scattered 16B stores => 2.6x write amplification (168MB).
// R9: splitting partial_split (2nd x read) cost more than it saved.
// R10: merged prep kernels; kcs folded into attn_proj. 230us.
// R11: per-lane sparsity skip NULL on wave64 (wave executes every body).
// R12: attn reduce moved to MFMA (exact integer arithmetic) -> 217us. BEST.
// R13 lesson: region/scores fold into rescue = 80KB LDS for ALL blocks
// (occupancy 2%) + 64-way bank-conflict dot loop (reg row stride 1024B ->
// bank = c%32 for every lane) in only 2 blocks -> 88us long pole. REVERTED
// to the exact R12 configuration (measured 217.1us).
#define OFF_A2     0ull            // [mb][gi 0..7][ktA 0..15][lane][8] = 64 MB
#define OFF_BQ     67108864ull     // [gj 0..47][ktB 0..7][lane][8] = 393,216 (hi only)
#define OFF_BP     67502080ull     // [gj 0..15][ktB 0..23][lane][8] = 393,216 (3-term)
#define OFF_QM     67895296ull     // qmask u32 [g][s][h] = 2,097,152
#define OFF_KB     69992448ull     // 2,097,152
#define OFF_VB     72089600ull     // 2,097,152
#define OFF_KV     74186752ull     // kvf bf16 2-term B-frags = 16,777,216
#define OFF_PART   91488256ull     // 524,288
#define OFF_REGION 92012544ull     // 131,072
#define OFF_IDX    92143616ull     // 2,048
#define OFF_RL     92145664ull     // 524,288 (131072 entries)
#define OFF_RC     92669952ull     // 16

typedef short short8 __attribute__((ext_vector_type(8)));
typedef float floatx4 __attribute__((ext_vector_type(4)));

__device__ __forceinline__ short f2bf(float f) {
    unsigned u = __float_as_uint(f);
    unsigned r = (u + 0x7fffu + ((u >> 16) & 1u)) >> 16;
    return (short)r;
}
__device__ __forceinline__ float bf2f(short h) {
    return __uint_as_float(((unsigned)(unsigned short)h) << 16);
}

__device__ __forceinline__ void gload_lds16(const void* g, void* l) {
    __builtin_amdgcn_global_load_lds(
        (const __attribute__((address_space(1))) unsigned*)g,
        (__attribute__((address_space(3))) unsigned*)l,
        16, 0, 0);
}

// g = (t*B_+b)*NW_ + n, s in [0,128): float index of x[t,b,lt,lh,lw,0]
__device__ __forceinline__ int xoff_row(int g, int s) {
    int tb = g >> 6;
    int n  = g & 63;
    int iwt = n >> 4, iwh = (n >> 2) & 3, iww = n & 3;
    int ipt = s >> 6, iph = (s >> 3) & 7, ipw = s & 7;
    int lt = iwt * 2 + ipt, lh = iwh * 8 + iph, lw = iww * 8 + ipw;
    return (((tb * 8 + lt) * 32 + lh) * 32 + lw) * 256;
}

// ---- PREP: one launch, three independent jobs branched on blockIdx.
__global__ __launch_bounds__(256) void k_prep(const float* __restrict__ x,
        const float* __restrict__ Wqkv, const float* __restrict__ Wp,
        float* __restrict__ part, short* __restrict__ A2,
        short* __restrict__ Bq, short* __restrict__ Bp) {
    const int bid = blockIdx.x;
    const int tid = threadIdx.x;
    if (bid < 512) {
        // partial_split (exact R7 fused version: one x read, ascending-s)
        int g = bid;
        int c = tid;
        const int ktAh = c >> 5, ktAl = 8 + (c >> 5);
        const int octsh = ((c >> 3) & 3) << 4, sub = c & 7;
        float acc = 0.f;
        for (int s = 0; s < WS_; ++s) {
            float v = x[xoff_row(g, s) + c];
            acc += v;
            short hi = f2bf(v);
            short lo = f2bf(v - bf2f(hi));
            int lane = (s & 15) | octsh;
            size_t base = ((size_t)(g * 8 + (s >> 4))) * 16;
            A2[(base + ktAh) * 512 + lane * 8 + sub] = hi;
            A2[(base + ktAl) * 512 + lane * 8 + sub] = lo;
        }
        part[g * C_ + c] = acc;
    } else if (bid < 1280) {
        // b_build_qkv: u = ke + 256*ny
        int u = bid - 512;
        int ke = u & 255;
        int n = (u >> 8) * 256 + tid;
        float wv = Wqkv[(size_t)ke * NC3 + n];
        short o = f2bf(wv);
        int gj = n >> 4, lmn = n & 15, ktB = ke >> 5, oct = (ke >> 3) & 3, sub = ke & 7;
        Bq[(size_t)((gj * 8 + ktB) * 64 + (lmn | (oct << 4))) * 8 + sub] = o;
    } else {
        // b_build_proj
        int ke = bid - 1280;               // 0..767
        int n = tid;
        float wv = Wp[(size_t)(ke & 255) * 256 + n];
        short hi = f2bf(wv);
        short o = (ke < 512) ? hi : f2bf(wv - bf2f(hi));
        int gj = n >> 4, lmn = n & 15, ktB = ke >> 5, oct = (ke >> 3) & 3, sub = ke & 7;
        Bp[(size_t)((gj * 24 + ktB) * 64 + (lmn | (oct << 4))) * 8 + sub] = o;
    }
}

// ---- K1b: region[b,n,c] = sum_t part / 128 ----
__global__ __launch_bounds__(256) void k_region(const float* __restrict__ part,
                                                float* __restrict__ region) {
    int bn = blockIdx.x;           // 128
    int c = threadIdx.x;
    int b = bn >> 6, n = bn & 63;
    float acc = 0.f;
    for (int t = 0; t < T_; ++t) acc += part[((t * 2 + b) * 64 + n) * C_ + c];
    region[bn * C_ + c] = acc * (1.0f / 128.0f);
}

// ---- K2: scores + top-4 (lowest-index tie-break) ----
__global__ __launch_bounds__(64) void k_scores(const float* __restrict__ region,
                                               int* __restrict__ idx) {
    int bi = blockIdx.x;           // 128
    int b = bi >> 6, i = bi & 63;
    int tid = threadIdx.x;
    __shared__ float ri[C_];
    __shared__ float sc[64];
    for (int c = tid; c < C_; c += 64) ri[c] = region[(b * 64 + i) * C_ + c];
    __syncthreads();
    const float* rj = region + (size_t)(b * 64 + tid) * C_;
    float dot = 0.f;
    for (int c = 0; c < C_; ++c) dot += ri[c] * rj[c];
    sc[tid] = dot * 0.17677669529663687f;
    __syncthreads();
    if (tid == 0) {
        for (int kk = 0; kk < TOPK_; ++kk) {
            float best = -INFINITY; int bj = 0;
            for (int j = 0; j < 64; ++j)
                if (sc[j] > best) { best = sc[j]; bj = j; }
            idx[bi * TOPK_ + kk] = bj;
            sc[bj] = -INFINITY;
        }
    }
}

__device__ __forceinline__ unsigned p4(unsigned xv) {
    return (xv & 1u) | ((xv >> 7) & 2u) | ((xv >> 14) & 4u) | ((xv >> 21) & 8u);
}

// ---- K3: qkv GEMM, LDS-staged (m97 pattern). FROZEN (R7, 82 us).
__global__ __launch_bounds__(256, 2) void qkv_mfma(const short* __restrict__ A2,
        const short* __restrict__ Bq, const float* __restrict__ bias,
        unsigned* __restrict__ qm, unsigned* __restrict__ kb,
        unsigned* __restrict__ vb, unsigned* __restrict__ rl,
        unsigned* __restrict__ rcnt) {
    __shared__ __align__(16) char stg[2][32768];   // staging; [0] reused as sp
    __shared__ unsigned rbuf[RBCAP];
    __shared__ unsigned lcnt, sbase;
    const int bid = blockIdx.x;            // 0..1535
    const int x8 = bid & 7;
    const int y = bid >> 3;                // 0..191
    const int p = y % 3;
    const int mb = x8 + ((y / 3) << 3);    // bijective: all (mb,p) covered
    const int tid = threadIdx.x;
    const int wv = tid >> 6, lane = tid & 63;
    const int wm = wv >> 1, wn = wv & 1;
    const int lm = lane & 15, lq = lane >> 4;

    if (tid == 0) lcnt = 0;

    const char* Ag = (const char*)(A2 + (size_t)mb * 65536);   // 128 KB slice
    const char* Bg = (const char*)(Bq + (size_t)p * 65536);    // 128 KB slice
    const int laneoff = lane * 16;

#define STAGE_CHUNK(buf, ktB_)                                                 \
    {                                                                          \
        _Pragma("unroll")                                                      \
        for (int k = 0; k < 4; ++k) {                                          \
            int slot = k * 4 + wv;                                             \
            int gi = slot >> 1, hl = slot & 1;                                 \
            const char* src = Ag + (((gi * 16) + (ktB_) + hl * 8) << 10) + laneoff; \
            gload_lds16(src, &stg[buf][k * 4096 + wv * 1024 + laneoff]);       \
        }                                                                      \
        _Pragma("unroll")                                                      \
        for (int k = 0; k < 4; ++k) {                                          \
            int slot = k * 4 + wv;                                             \
            const char* src = Bg + ((slot * 8 + (ktB_)) << 10) + laneoff;      \
            gload_lds16(src, &stg[buf][16384 + k * 4096 + wv * 1024 + laneoff]); \
        }                                                                      \
    }

    floatx4 acc[4][8];
#pragma unroll
    for (int i = 0; i < 4; ++i)
#pragma unroll
        for (int j = 0; j < 8; ++j) acc[i][j] = (floatx4)0.f;

    STAGE_CHUNK(0, 0);
    __syncthreads();                       // drains stage 0 (vmcnt(0))

    for (int ktB = 0; ktB < 8; ++ktB) {
        int cur = ktB & 1;
        if (ktB < 7) STAGE_CHUNK(cur ^ 1, ktB + 1);
        const char* sb = &stg[cur][0];
        short8 ah[4], al[4], bf[8];
#pragma unroll
        for (int j = 0; j < 8; ++j)
            bf[j] = *(const short8*)(sb + 16384 + ((wn * 8 + j) << 10) + laneoff);
#pragma unroll
        for (int i = 0; i < 4; ++i) {
            ah[i] = *(const short8*)(sb + (((wm * 4 + i) * 2 + 0) << 10) + laneoff);
            al[i] = *(const short8*)(sb + (((wm * 4 + i) * 2 + 1) << 10) + laneoff);
        }
#pragma unroll
        for (int i = 0; i < 4; ++i)
#pragma unroll
            for (int j = 0; j < 8; ++j)
                acc[i][j] = __builtin_amdgcn_mfma_f32_16x16x32_bf16(
                    ah[i], bf[j], acc[i][j], 0, 0, 0);
#pragma unroll
        for (int i = 0; i < 4; ++i)
#pragma unroll
            for (int j = 0; j < 8; ++j)
                acc[i][j] = __builtin_amdgcn_mfma_f32_16x16x32_bf16(
                    al[i], bf[j], acc[i][j], 0, 0, 0);
        __syncthreads();   // all waves done reading cur; next stage drained
    }

    // epilogue: spikes into LDS (sp aliases stg); borderline -> rescue staging
    unsigned char* sp = (unsigned char*)&stg[0][0];   // 128*264 = 33792 <= 65536
#pragma unroll
    for (int i = 0; i < 4; ++i) {
#pragma unroll
        for (int j = 0; j < 8; ++j) {
            int cb = wn * 128 + j * 16 + lm;
            int cg = p * 256 + cb;
            float bj = bias[cg];
#pragma unroll
            for (int r = 0; r < 4; ++r) {
                int s = wm * 64 + i * 16 + lq * 4 + r;
                float v = acc[i][j][r] + bj;
                if (fabsf(v - 2.0f) < BAND) {
                    unsigned ent = ((unsigned)mb << 17) | ((unsigned)s << 10) | (unsigned)cg;
                    unsigned slot = atomicAdd(&lcnt, 1u);
                    if (slot < RBCAP) {
                        rbuf[slot] = ent;
                    } else {                       // overflow fallback (cold)
                        unsigned gs = atomicAdd(rcnt, 1u);
                        if (gs < RCAP) rl[gs] = ent;
                    }
                }
                sp[s * 264 + cb] = (v >= 2.0f) ? 1 : 0;
            }
        }
    }
    __syncthreads();

    // bulk-reserve rescue slots: ONE global atomic per block
    unsigned cnt = lcnt;
    if (cnt > RBCAP) cnt = RBCAP;
    if (tid == 0) sbase = atomicAdd(rcnt, cnt);
    __syncthreads();
    for (unsigned e = tid; e < cnt; e += 256) {
        unsigned slot = sbase + e;
        if (slot < RCAP) rl[slot] = rbuf[e];
    }

    if (p == 0) {
        // pack q bitmasks over channel-within-head: qm[g][s][h]
        const unsigned* spw = (const unsigned*)sp;   // pitch 66 words
#pragma unroll
        for (int t = 0; t < 4; ++t) {
            int w = t * 256 + tid;
            int s = w >> 3, h = w & 7;
            unsigned m = 0;
#pragma unroll
            for (int q = 0; q < 8; ++q)
                m |= p4(spw[s * 66 + h * 8 + q]) << (q * 4);
            qm[(size_t)mb * 1024 + w] = m;
        }
    } else {
        // pack k/v bitmasks along s: (kb|vb)[(mb*256+c)*4 + w2]
        unsigned wrd[4];
#pragma unroll
        for (int w2 = 0; w2 < 4; ++w2) {
            unsigned m = 0;
#pragma unroll
            for (int ii = 0; ii < 32; ++ii)
                m |= (unsigned)(sp[(w2 * 32 + ii) * 264 + tid] & 1) << ii;
            wrd[w2] = m;
        }
        uint4 o; o.x = wrd[0]; o.y = wrd[1]; o.z = wrd[2]; o.w = wrd[3];
        *(uint4*)(((p == 1) ? kb : vb) + ((size_t)mb * 256 + tid) * 4) = o;
    }
}

// ---- rescue: LANE-PARALLEL serial ascending-k fp32 FMA per entry. ----
__global__ __launch_bounds__(256) void rescue_fix(const float* __restrict__ x,
        const float* __restrict__ W, const float* __restrict__ bias,
        const unsigned* __restrict__ rl, const unsigned* __restrict__ rcnt,
        unsigned* __restrict__ qm, unsigned* __restrict__ kb,
        unsigned* __restrict__ vb) {
    unsigned n = *rcnt; if (n > RCAP) n = RCAP;
    unsigned gid = blockIdx.x * 256 + threadIdx.x;
    unsigned stride = gridDim.x * 256;
    for (unsigned e = gid; e < n; e += stride) {
        unsigned ent = rl[e];
        int mb = ent >> 17, s = (ent >> 10) & 127, cg = ent & 1023;
        const float* ar = x + xoff_row(mb, s);
        const float* wc = W + cg;
        float da = 0.f;
#pragma unroll 4
        for (int k4 = 0; k4 < 64; ++k4) {
            float4 a4 = *(const float4*)(ar + k4 * 4);
            da = fmaf(a4.x, wc[(size_t)(k4 * 4 + 0) * NC3], da);
            da = fmaf(a4.y, wc[(size_t)(k4 * 4 + 1) * NC3], da);
            da = fmaf(a4.z, wc[(size_t)(k4 * 4 + 2) * NC3], da);
            da = fmaf(a4.w, wc[(size_t)(k4 * 4 + 3) * NC3], da);
        }
        da += bias[cg];
        int spk = (da >= 2.0f) ? 1 : 0;
        if (cg < 256) {
            int h = cg >> 5, d = cg & 31;
            unsigned* wp = qm + (size_t)mb * 1024 + s * 8 + h;
            unsigned bit = 1u << d;
            int have = (*wp & bit) ? 1 : 0;
            if (have != spk) atomicXor(wp, bit);
        } else {
            unsigned* tgt = (cg < 512) ? kb : vb;
            int c = cg & 255;
            unsigned* wp = tgt + ((size_t)mb * 256 + c) * 4 + (s >> 5);
            unsigned bit = 1u << (s & 31);
            int have = (*wp & bit) ? 1 : 0;
            if (have != spk) atomicXor(wp, bit);
        }
    }
}

// ---- K4: kv = popcount over gathered s-bitmasks (exact int <= 512),
// written PRE-PACKED as bf16 2-term B-fragments for the attn MFMA.
__global__ __launch_bounds__(256) void kv_bits(const unsigned* __restrict__ kb,
        const unsigned* __restrict__ vb, const int* __restrict__ idx,
        short* __restrict__ kvf) {
    int g = blockIdx.x;            // 512
    int tb = g >> 6, n = g & 63, b = tb & 1;
    int tid = threadIdx.x;
    __shared__ uint4 kbl[1024];
    __shared__ uint4 vbl[1024];
    __shared__ int widx[TOPK_];
    if (tid < TOPK_) widx[tid] = idx[(b * 64 + n) * TOPK_ + tid];
    __syncthreads();
#pragma unroll
    for (int kk = 0; kk < TOPK_; ++kk) {
        int g2 = tb * 64 + widx[kk];
        kbl[kk * 256 + tid] = *(const uint4*)&kb[((size_t)g2 * 256 + tid) * 4];
        vbl[kk * 256 + tid] = *(const uint4*)&vb[((size_t)g2 * 256 + tid) * 4];
    }
    __syncthreads();
    int h = tid >> 5, e = tid & 31;
    int ei = e >> 4;
    uint4 vw0 = vbl[0 * 256 + h * 32 + e];
    uint4 vw1 = vbl[1 * 256 + h * 32 + e];
    uint4 vw2 = vbl[2 * 256 + h * 32 + e];
    uint4 vw3 = vbl[3 * 256 + h * 32 + e];
#pragma unroll
    for (int oct = 0; oct < 4; ++oct) {
        short8 hi8, lo8;
#pragma unroll
        for (int dd = 0; dd < 8; ++dd) {
            int d = oct * 8 + dd;
            uint4 k0 = kbl[0 * 256 + h * 32 + d];
            uint4 k1 = kbl[1 * 256 + h * 32 + d];
            uint4 k2 = kbl[2 * 256 + h * 32 + d];
            uint4 k3 = kbl[3 * 256 + h * 32 + d];
            int acc = __popc(k0.x & vw0.x) + __popc(k0.y & vw0.y)
                    + __popc(k0.z & vw0.z) + __popc(k0.w & vw0.w)
                    + __popc(k1.x & vw1.x) + __popc(k1.y & vw1.y)
                    + __popc(k1.z & vw1.z) + __popc(k1.w & vw1.w)
                    + __popc(k2.x & vw2.x) + __popc(k2.y & vw2.y)
                    + __popc(k2.z & vw2.z) + __popc(k2.w & vw2.w)
                    + __popc(k3.x & vw3.x) + __popc(k3.y & vw3.y)
                    + __popc(k3.z & vw3.z) + __popc(k3.w & vw3.w);
            float v = (float)acc;
            short hv = f2bf(v);            // exact split: lo in {-1,0,1}
            hi8[dd] = hv;
            lo8[dd] = f2bf(v - bf2f(hv));
        }
        int ln = (e & 15) | (oct << 4);
        *(short8*)&kvf[((((size_t)g * 8 + h) * 2 + 0) * 2 + ei) * 512 + ln * 8] = hi8;
        *(short8*)&kvf[((((size_t)g * 8 + h) * 2 + 1) * 2 + ei) * 512 + ln * 8] = lo8;
    }
}

// ---- K5: FUSED attn + proj. One block = 32 rows of one window g. ----
// R12: attn phase on MFMA. num = Q x (KVhi + KVlo), den via 32 cndmask-adds.
// Exact integer arithmetic -> bit-identical r.
__global__ __launch_bounds__(256) void attn_proj(const unsigned* __restrict__ qm,
        const short* __restrict__ kvf, const unsigned* __restrict__ kb,
        const int* __restrict__ idx, const short* __restrict__ Bp,
        const float* __restrict__ bias, float* __restrict__ out) {
    __shared__ __align__(16) short aw[16384];   // 32 KB frags; reused as float ow[32][256]
    __shared__ unsigned qb[256];
    __shared__ float ksl[256];
    __shared__ float denl[256];
    __shared__ int widx[TOPK_];
    const int bid = blockIdx.x;        // 2048
    const int g = bid >> 2, qr = bid & 3;
    const int tb = g >> 6, n = g & 63, b = tb & 1;
    const int tid = threadIdx.x;
    if (tid < TOPK_) widx[tid] = idx[(b * 64 + n) * TOPK_ + tid];
    __syncthreads();
    float ks = 0.f;
#pragma unroll
    for (int kk = 0; kk < TOPK_; ++kk) {
        uint4 kw = *(const uint4*)&kb[((size_t)(tb * 64 + widx[kk]) * 256 + tid) * 4];
        ks += (float)(__popc(kw.x) + __popc(kw.y) + __popc(kw.z) + __popc(kw.w));
    }
    ksl[tid] = ks;
    qb[tid] = qm[(size_t)g * 1024 + qr * 256 + tid];
    __syncthreads();

    // den[h][sl]: one thread per (h, sl); ascending-d adds of exact integers
    {
        int h = tid >> 5, sl = tid & 31;
        unsigned qw = qb[sl * 8 + h];
        float den = 0.f;
#pragma unroll
        for (int d = 0; d < 32; ++d)
            den += ((qw >> d) & 1u) ? ksl[h * 32 + d] : 0.f;
        denl[tid] = den;
    }
    __syncthreads();

    const int wvw = tid >> 6, lane = tid & 63;
    const int oct = lane >> 4, l15 = lane & 15;

    // attn MFMA: wave owns heads {2*wvw, 2*wvw+1}
    floatx4 nacc[2][2][2];   // [h2][mi][ei]
#pragma unroll
    for (int h2 = 0; h2 < 2; ++h2)
#pragma unroll
        for (int mi = 0; mi < 2; ++mi)
#pragma unroll
            for (int ei = 0; ei < 2; ++ei) nacc[h2][mi][ei] = (floatx4)0.f;

#pragma unroll
    for (int h2 = 0; h2 < 2; ++h2) {
        int h = wvw * 2 + h2;
        // A-frags: Q bits -> bf16 {0, 1.0}; lane holds k = oct*8 + j
        short8 a0, a1;
        {
            unsigned byt = (qb[(l15)*8 + h] >> (oct * 8)) & 0xffu;
#pragma unroll
            for (int j = 0; j < 8; ++j)
                a0[j] = ((byt >> j) & 1u) ? (short)0x3F80 : (short)0;
        }
        {
            unsigned byt = (qb[(16 + l15)*8 + h] >> (oct * 8)) & 0xffu;
#pragma unroll
            for (int j = 0; j < 8; ++j)
                a1[j] = ((byt >> j) & 1u) ? (short)0x3F80 : (short)0;
        }
#pragma unroll
        for (int ei = 0; ei < 2; ++ei) {
            short8 bh = *(const short8*)&kvf[((((size_t)g * 8 + h) * 2 + 0) * 2 + ei) * 512 + lane * 8];
            short8 bl = *(const short8*)&kvf[((((size_t)g * 8 + h) * 2 + 1) * 2 + ei) * 512 + lane * 8];
            nacc[h2][0][ei] = __builtin_amdgcn_mfma_f32_16x16x32_bf16(a0, bh, nacc[h2][0][ei], 0, 0, 0);
            nacc[h2][0][ei] = __builtin_amdgcn_mfma_f32_16x16x32_bf16(a0, bl, nacc[h2][0][ei], 0, 0, 0);
            nacc[h2][1][ei] = __builtin_amdgcn_mfma_f32_16x16x32_bf16(a1, bh, nacc[h2][1][ei], 0, 0, 0);
            nacc[h2][1][ei] = __builtin_amdgcn_mfma_f32_16x16x32_bf16(a1, bl, nacc[h2][1][ei], 0, 0, 0);
        }
    }

    // epilogue: divide by den, split hi/lo, write aw A-frags (same layout as old)
#pragma unroll
    for (int h2 = 0; h2 < 2; ++h2) {
        int h = wvw * 2 + h2;
#pragma unroll
        for (int mi = 0; mi < 2; ++mi) {
#pragma unroll
            for (int ei = 0; ei < 2; ++ei) {
                int e = ei * 16 + l15;
                int lane2base = (((e >> 3) & 3) << 4);
                int sub = e & 7;
#pragma unroll
                for (int r = 0; r < 4; ++r) {
                    int sl = mi * 16 + oct * 4 + r;
                    float rv = nacc[h2][mi][ei][r] / (denl[h * 32 + sl] + 1e-6f);
                    short hi = f2bf(rv), lo = f2bf(rv - bf2f(hi));
                    int lane2 = (sl & 15) | lane2base;
                    aw[((mi * 16 + h) * 64 + lane2) * 8 + sub] = hi;
                    aw[((mi * 16 + 8 + h) * 64 + lane2) * 8 + sub] = lo;
                }
            }
        }
    }
    __syncthreads();

    // proj: M=32, N=256; 4 waves each N=64
    const int lm = lane & 15, lq = lane >> 4;
    floatx4 pacc[2][4];
#pragma unroll
    for (int i = 0; i < 2; ++i)
#pragma unroll
        for (int j = 0; j < 4; ++j) pacc[i][j] = (floatx4)0.f;
    const short* Bb = Bp + ((size_t)(wvw * 4) * 24) * 512 + lane * 8;
#pragma unroll 2
    for (int kt = 0; kt < 24; ++kt) {
        int ktA = (kt < 16) ? kt : kt - 16;
        short8 af[2], bf[4];
#pragma unroll
        for (int i = 0; i < 2; ++i)
            af[i] = *(const short8*)&aw[((i * 16 + ktA) * 64 + lane) * 8];
#pragma unroll
        for (int j = 0; j < 4; ++j)
            bf[j] = *(const short8*)(Bb + (size_t)(j * 24 + kt) * 512);
#pragma unroll
        for (int i = 0; i < 2; ++i)
#pragma unroll
            for (int j = 0; j < 4; ++j)
                pacc[i][j] = __builtin_amdgcn_mfma_f32_16x16x32_bf16(
                    af[i], bf[j], pacc[i][j], 0, 0, 0);
    }
    __syncthreads();

    float* ow = (float*)aw;            // 32 x 256 fp32 rows
#pragma unroll
    for (int i = 0; i < 2; ++i) {
#pragma unroll
        for (int j = 0; j < 4; ++j) {
            int c = wvw * 64 + j * 16 + lm;
            float bj = bias[c];
#pragma unroll
            for (int r = 0; r < 4; ++r)
                ow[(i * 16 + lq * 4 + r) * 256 + c] = pacc[i][j][r] + bj;
        }
    }
    __syncthreads();

    // coalesced un-windowize store: rows are contiguous 1 KB in out
    int sl2 = tid >> 3, pc = (tid & 7) * 32;
    int off = xoff_row(g, qr * 32 + sl2) + pc;
#pragma unroll
    for (int q = 0; q < 8; ++q)
        *(float4*)(out + off + q * 4) = *(const float4*)&ow[sl2 * 256 + pc + q * 4];
}

extern "C" void kernel_launch(void* const* d_in, const int* in_sizes, int n_in,
                              void* d_out, int out_size, void* d_ws, size_t ws_size,
                              hipStream_t stream) {
    (void)in_sizes; (void)n_in; (void)out_size; (void)ws_size;
    const float* x    = (const float*)d_in[0];
    const float* Wqkv = (const float*)d_in[1];
    const float* bqkv = (const float*)d_in[2];
    const float* Wp   = (const float*)d_in[3];
    const float* bp   = (const float*)d_in[4];
    char* ws = (char*)d_ws;
    short*    A2    = (short*)   (ws + OFF_A2);
    short*    Bq    = (short*)   (ws + OFF_BQ);
    short*    Bpj   = (short*)   (ws + OFF_BP);
    unsigned* qmv   = (unsigned*)(ws + OFF_QM);
    unsigned* kb    = (unsigned*)(ws + OFF_KB);
    unsigned* vb    = (unsigned*)(ws + OFF_VB);
    short*    kvf   = (short*)   (ws + OFF_KV);
    float*    part  = (float*)   (ws + OFF_PART);
    float*    region= (float*)   (ws + OFF_REGION);
    int*      idxb  = (int*)     (ws + OFF_IDX);
    unsigned* rl    = (unsigned*)(ws + OFF_RL);
    unsigned* rcnt  = (unsigned*)(ws + OFF_RC);
    float*    out   = (float*)d_out;

    hipMemsetAsync(rcnt, 0, 4, stream);
    k_prep     <<<2048, 256, 0, stream>>>(x, Wqkv, Wp, part, A2, Bq, Bpj);
    k_region   <<<128, 256, 0, stream>>>(part, region);
    k_scores   <<<128,  64, 0, stream>>>(region, idxb);
    qkv_mfma   <<<1536, 256, 0, stream>>>(A2, Bq, bqkv, qmv, kb, vb, rl, rcnt);
    rescue_fix <<<256, 256, 0, stream>>>(x, Wqkv, bqkv, rl, rcnt, qmv, kb, vb);
    kv_bits    <<<512, 256, 0, stream>>>(kb, vb, idxb, kvf);
    attn_proj  <<<2048, 256, 0, stream>>>(qmv, kvf, kb, idxb, Bpj, bp, out);
}